// Round 2
// baseline (3716.171 us; speedup 1.0000x reference)
//
#include <hip/hip_runtime.h>
#include <cstdint>
#include <cstddef>

#define BB 256
#define TT 3000
#define II 40
#define HH 64
#define GG 256  // 4*H

__device__ __forceinline__ float sigmoidf_(float x) {
  return __fdividef(1.0f, 1.0f + __expf(-x));
}
__device__ __forceinline__ float tanhf_(float x) {
  // exact identity: tanh(x) = 1 - 2/(e^{2x}+1); saturates cleanly at +-inf
  float t = __expf(2.0f * x);
  return 1.0f - __fdividef(2.0f, t + 1.0f);
}

// One block per (batch, direction). 256 threads; thread g owns gate row g.
// W_ih row (40 f32) + W_hh row (64 f32) held in registers. h broadcast via LDS.
__global__ __launch_bounds__(256, 2) void bilstm_kernel(
    const float* __restrict__ x,
    const float* __restrict__ W_ih_f, const float* __restrict__ W_hh_f,
    const float* __restrict__ b_ih_f, const float* __restrict__ b_hh_f,
    const float* __restrict__ W_ih_b, const float* __restrict__ W_hh_b,
    const float* __restrict__ b_ih_b, const float* __restrict__ b_hh_b,
    float* __restrict__ hcat) {
  const int tid = threadIdx.x;
  const int b   = blockIdx.x & (BB - 1);
  const int dir = blockIdx.x >> 8;

  const float* W_ih = dir ? W_ih_b : W_ih_f;
  const float* W_hh = dir ? W_hh_b : W_hh_f;
  const float* b_ih = dir ? b_ih_b : b_ih_f;
  const float* b_hh = dir ? b_hh_b : b_hh_f;

  __shared__ float4 xb4[II / 4];   // 40 floats of x[b,t,:]
  __shared__ float4 h4[HH / 4];    // 64 floats of h
  __shared__ float  gates[GG];     // post-activation gates

  // Per-thread weight rows -> registers (fully unrolled, const indices)
  float4 wih[10];
  {
    const float4* p = (const float4*)(W_ih + (size_t)tid * II);
#pragma unroll
    for (int k = 0; k < 10; ++k) wih[k] = p[k];
  }
  float4 whh[16];
  {
    const float4* p = (const float4*)(W_hh + (size_t)tid * HH);
#pragma unroll
    for (int k = 0; k < 16; ++k) whh[k] = p[k];
  }
  const float bias = b_ih[tid] + b_hh[tid];

  if (tid < HH) ((float*)h4)[tid] = 0.0f;
  float c = 0.0f;

  const float* xrow_base = x + (size_t)b * TT * II;
  float* hout_base = hcat + (size_t)b * TT * 128 + dir * HH;

  for (int t = 0; t < TT; ++t) {
    const int tt = dir ? (TT - 1 - t) : t;

    // stage x[b,tt,:] into LDS (40 consecutive floats, one coalesced fetch)
    if (tid < II) ((float*)xb4)[tid] = xrow_base[(size_t)tt * II + tid];
    __syncthreads();  // publishes xbuf (this iter) + h (prev iter)

    // gate pre-activation: bias + W_ih[g,:].x + W_hh[g,:].h
    // 4 independent accumulator chains (float4 lanes) to hide FMA latency
    float4 a; a.x = bias; a.y = 0.0f; a.z = 0.0f; a.w = 0.0f;
#pragma unroll
    for (int k = 0; k < 10; ++k) {
      float4 xv = xb4[k];
      a.x = fmaf(wih[k].x, xv.x, a.x);
      a.y = fmaf(wih[k].y, xv.y, a.y);
      a.z = fmaf(wih[k].z, xv.z, a.z);
      a.w = fmaf(wih[k].w, xv.w, a.w);
    }
#pragma unroll
    for (int k = 0; k < 16; ++k) {
      float4 hv = h4[k];
      a.x = fmaf(whh[k].x, hv.x, a.x);
      a.y = fmaf(whh[k].y, hv.y, a.y);
      a.z = fmaf(whh[k].z, hv.z, a.z);
      a.w = fmaf(whh[k].w, hv.w, a.w);
    }
    float acc = (a.x + a.y) + (a.z + a.w);

    // per-gate activation, wave-uniform branch: rows [128,192) = tanh (wave 2)
    float act = ((tid >> 6) == 2) ? tanhf_(acc) : sigmoidf_(acc);
    gates[tid] = act;
    __syncthreads();

    // cell update (one wave; single tanh on critical path)
    if (tid < HH) {
      float gi = gates[tid];
      float gf = gates[HH + tid];
      float gg = gates[2 * HH + tid];
      float go = gates[3 * HH + tid];
      c = fmaf(gf, c, gi * gg);
      float h = go * tanhf_(c);
      ((float*)h4)[tid] = h;
      hout_base[(size_t)tt * 128 + tid] = h;
    }
  }
}

// MLP head: out[bt] = sigmoid(W2 . relu(W1 . h128 + b1) + b2)
// Thread-per-output; W1 staged in LDS (wave-uniform broadcast reads);
// h row (128 f32) in registers.
__global__ __launch_bounds__(256, 2) void mlp_kernel(
    const float* __restrict__ hcat,
    const float* __restrict__ W1, const float* __restrict__ b1,
    const float* __restrict__ W2, const float* __restrict__ b2,
    float* __restrict__ out) {
  __shared__ float4 w1s[64 * 32];  // 64 rows x 128 floats = 32 KiB
  __shared__ float  b1s[64];
  __shared__ float  w2s[64];
  __shared__ float  b2s;

  const int tid = threadIdx.x;
  const float4* w1g = (const float4*)W1;
  for (int i = tid; i < 64 * 32; i += 256) w1s[i] = w1g[i];
  if (tid < 64) { b1s[tid] = b1[tid]; w2s[tid] = W2[tid]; }
  if (tid == 0) b2s = b2[0];
  __syncthreads();

  const size_t bt = (size_t)blockIdx.x * 256 + tid;  // grid sized exactly
  float4 hreg[32];
  const float4* hp = (const float4*)(hcat + bt * 128);
#pragma unroll
  for (int k = 0; k < 32; ++k) hreg[k] = hp[k];

  float acc2 = b2s;
  for (int o = 0; o < 64; ++o) {
    const float4* w = &w1s[o * 32];
    float4 a; a.x = 0.0f; a.y = 0.0f; a.z = 0.0f; a.w = 0.0f;
#pragma unroll
    for (int k = 0; k < 32; ++k) {
      float4 wv = w[k];
      a.x = fmaf(wv.x, hreg[k].x, a.x);
      a.y = fmaf(wv.y, hreg[k].y, a.y);
      a.z = fmaf(wv.z, hreg[k].z, a.z);
      a.w = fmaf(wv.w, hreg[k].w, a.w);
    }
    float z = b1s[o] + (a.x + a.y) + (a.z + a.w);
    z = fmaxf(z, 0.0f);
    acc2 = fmaf(w2s[o], z, acc2);
  }
  out[bt] = sigmoidf_(acc2);
}

extern "C" void kernel_launch(void* const* d_in, const int* in_sizes, int n_in,
                              void* d_out, int out_size, void* d_ws, size_t ws_size,
                              hipStream_t stream) {
  const float* x      = (const float*)d_in[0];
  const float* W_ih_f = (const float*)d_in[1];
  const float* W_hh_f = (const float*)d_in[2];
  const float* b_ih_f = (const float*)d_in[3];
  const float* b_hh_f = (const float*)d_in[4];
  const float* W_ih_b = (const float*)d_in[5];
  const float* W_hh_b = (const float*)d_in[6];
  const float* b_ih_b = (const float*)d_in[7];
  const float* b_hh_b = (const float*)d_in[8];
  const float* W1     = (const float*)d_in[9];
  const float* b1     = (const float*)d_in[10];
  const float* W2     = (const float*)d_in[11];
  const float* b2     = (const float*)d_in[12];
  float* out = (float*)d_out;
  float* hcat = (float*)d_ws;  // (B, T, 128) f32 = 393,216,000 bytes

  bilstm_kernel<<<dim3(2 * BB), dim3(256), 0, stream>>>(
      x, W_ih_f, W_hh_f, b_ih_f, b_hh_f, W_ih_b, W_hh_b, b_ih_b, b_hh_b, hcat);

  // B*T = 768000 = 3000 blocks * 256 threads exactly
  mlp_kernel<<<dim3(3000), dim3(256), 0, stream>>>(hcat, W1, b1, W2, b2, out);
}

// Round 4
// 2617.062 us; speedup vs baseline: 1.4200x; 1.4200x over previous
//
#include <hip/hip_runtime.h>
#include <hip/hip_bf16.h>
#include <cstdint>
#include <cstddef>

#define BB 256
#define TT 3000
#define II 40
#define HH 64
#define GG 256  // 4*H

__device__ __forceinline__ float sigmoidf_(float x) {
  return __fdividef(1.0f, 1.0f + __expf(-x));
}
__device__ __forceinline__ float tanhf_(float x) {
  float t = __expf(2.0f * x);
  return 1.0f - __fdividef(2.0f, t + 1.0f);
}
__device__ __forceinline__ float bf16bits_lo(unsigned u) {
  unsigned v = u << 16;
  return __uint_as_float(v);
}
__device__ __forceinline__ float bf16bits_hi(unsigned u) {
  unsigned v = u & 0xFFFF0000u;
  return __uint_as_float(v);
}

// One block per (batch, direction). 4 waves; wave w, lane l owns gate row 64w+l.
// Each wave keeps a PRIVATE replica of h (own LDS) and c (per-lane reg) and does
// the cell update redundantly -> only ONE cross-wave exchange (gates) per step.
// Raw s_barrier with lgkmcnt(0) only: global loads/stores never drained at the
// barrier. x prefetched 2 steps ahead (unroll-by-2, static parity).
__global__ __launch_bounds__(256, 2) void bilstm_kernel(
    const float* __restrict__ x,
    const float* __restrict__ W_ih_f, const float* __restrict__ W_hh_f,
    const float* __restrict__ b_ih_f, const float* __restrict__ b_hh_f,
    const float* __restrict__ W_ih_b, const float* __restrict__ W_hh_b,
    const float* __restrict__ b_ih_b, const float* __restrict__ b_hh_b,
    __hip_bfloat16* __restrict__ hcat) {
  const int tid  = threadIdx.x;
  const int lane = tid & 63;
  const int w    = tid >> 6;
  const int b    = blockIdx.x & (BB - 1);
  const int dir  = blockIdx.x >> 8;

  const float* W_ih = dir ? W_ih_b : W_ih_f;
  const float* W_hh = dir ? W_hh_b : W_hh_f;
  const float* b_ih = dir ? b_ih_b : b_ih_f;
  const float* b_hh = dir ? b_hh_b : b_hh_f;

  __shared__ float h_w[4][HH];       // per-wave h replica
  __shared__ float x_w[4][2][II];    // per-wave x double buffer (parity)
  __shared__ float gsm[2][GG];       // activated gates, double-buffered

  // gate-row weights -> registers
  float4 wih[10];
  {
    const float4* p = (const float4*)(W_ih + (size_t)tid * II);
#pragma unroll
    for (int k = 0; k < 10; ++k) wih[k] = p[k];
  }
  float4 whh[16];
  {
    const float4* p = (const float4*)(W_hh + (size_t)tid * HH);
#pragma unroll
    for (int k = 0; k < 16; ++k) whh[k] = p[k];
  }
  const float bias = b_ih[tid] + b_hh[tid];

  float c = 0.0f;
  h_w[w][lane] = 0.0f;  // own-wave init, no barrier needed

  const float* xb = x + (size_t)b * TT * II;
  __hip_bfloat16* hout = hcat + (size_t)b * TT * 128 + dir * HH;

  // time index helper: actual timestep for logical step t (clamped for prefetch)
#define TIDX(t_) (dir ? (TT - 1 - ((t_) < TT ? (t_) : TT - 1)) : ((t_) < TT ? (t_) : TT - 1))

  float xrA = 0.0f, xrB = 0.0f;
  if (lane < II) {
    x_w[w][0][lane] = xb[(size_t)TIDX(0) * II + lane];
    x_w[w][1][lane] = xb[(size_t)TIDX(1) * II + lane];
    xrA = xb[(size_t)TIDX(2) * II + lane];
    xrB = xb[(size_t)TIDX(3) * II + lane];
  }

  // STEP(t, parity, prefetch-reg): parity is compile-time constant.
#define STEP(T_, P_, XR_)                                                      \
  do {                                                                         \
    const int t_ = (T_);                                                       \
    /* gate pre-activation: bias + W_ih.x_t + W_hh.h  (own-wave LDS reads) */  \
    float4 a;                                                                  \
    a.x = bias; a.y = 0.0f; a.z = 0.0f; a.w = 0.0f;                            \
    const float4* xp = (const float4*)&x_w[w][P_][0];                          \
    _Pragma("unroll")                                                          \
    for (int k = 0; k < 10; ++k) {                                             \
      float4 xv = xp[k];                                                       \
      a.x = fmaf(wih[k].x, xv.x, a.x);                                         \
      a.y = fmaf(wih[k].y, xv.y, a.y);                                         \
      a.z = fmaf(wih[k].z, xv.z, a.z);                                         \
      a.w = fmaf(wih[k].w, xv.w, a.w);                                         \
    }                                                                          \
    const float4* hp = (const float4*)&h_w[w][0];                              \
    _Pragma("unroll")                                                          \
    for (int k = 0; k < 16; ++k) {                                             \
      float4 hv4 = hp[k];                                                      \
      a.x = fmaf(whh[k].x, hv4.x, a.x);                                        \
      a.y = fmaf(whh[k].y, hv4.y, a.y);                                        \
      a.z = fmaf(whh[k].z, hv4.z, a.z);                                        \
      a.w = fmaf(whh[k].w, hv4.w, a.w);                                        \
    }                                                                          \
    float acc = (a.x + a.y) + (a.z + a.w);                                     \
    /* wave-uniform activation: wave 2 = g-gate = tanh */                      \
    float act = (w == 2) ? tanhf_(acc) : sigmoidf_(acc);                       \
    gsm[P_][tid] = act;                                                        \
    /* one barrier per step; lgkmcnt(0) only — no vmcnt drain */               \
    asm volatile("s_waitcnt lgkmcnt(0)\n\ts_barrier" ::: "memory");            \
    /* cell update, redundant in every wave (lane l owns cell l) */            \
    float gi = gsm[P_][lane];                                                  \
    float gf = gsm[P_][HH + lane];                                             \
    float gg = gsm[P_][2 * HH + lane];                                         \
    float go = gsm[P_][3 * HH + lane];                                         \
    c = fmaf(gf, c, gi * gg);                                                  \
    float hv = go * tanhf_(c);                                                 \
    h_w[w][lane] = hv;                                                         \
    if (w == 0) hout[(size_t)TIDX(t_) * 128 + lane] = __float2bfloat16(hv);    \
    /* x pipeline: commit x_{t+2} (loaded 2 steps ago), issue x_{t+4} */       \
    if (lane < II) {                                                           \
      x_w[w][P_][lane] = XR_;                                                  \
      XR_ = xb[(size_t)TIDX(t_ + 4) * II + lane];                              \
    }                                                                          \
  } while (0)

  for (int t2 = 0; t2 < TT; t2 += 2) {
    STEP(t2, 0, xrA);
    STEP(t2 + 1, 1, xrB);
  }
#undef STEP
#undef TIDX
}

// MLP head: out[bt] = sigmoid(W2 . relu(W1 . h128 + b1) + b2), h in bf16.
__global__ __launch_bounds__(256, 2) void mlp_kernel(
    const unsigned* __restrict__ hcat,  // bf16 pairs packed in u32
    const float* __restrict__ W1, const float* __restrict__ b1,
    const float* __restrict__ W2, const float* __restrict__ b2,
    float* __restrict__ out) {
  __shared__ float4 w1s[64 * 32];  // 64 rows x 128 floats = 32 KiB
  __shared__ float  b1s[64];
  __shared__ float  w2s[64];
  __shared__ float  b2s;

  const int tid = threadIdx.x;
  const float4* w1g = (const float4*)W1;
  for (int i = tid; i < 64 * 32; i += 256) w1s[i] = w1g[i];
  if (tid < 64) { b1s[tid] = b1[tid]; w2s[tid] = W2[tid]; }
  if (tid == 0) b2s = b2[0];
  __syncthreads();

  const size_t bt = (size_t)blockIdx.x * 256 + tid;  // grid sized exactly
  // load 128 bf16 (256B) as 16 x uint4, expand to f32 in regs
  float4 hreg[32];
  const uint4* hp = (const uint4*)(hcat + bt * 64);
#pragma unroll
  for (int k = 0; k < 16; ++k) {
    uint4 u = hp[k];
    hreg[2 * k].x     = bf16bits_lo(u.x);
    hreg[2 * k].y     = bf16bits_hi(u.x);
    hreg[2 * k].z     = bf16bits_lo(u.y);
    hreg[2 * k].w     = bf16bits_hi(u.y);
    hreg[2 * k + 1].x = bf16bits_lo(u.z);
    hreg[2 * k + 1].y = bf16bits_hi(u.z);
    hreg[2 * k + 1].z = bf16bits_lo(u.w);
    hreg[2 * k + 1].w = bf16bits_hi(u.w);
  }

  float acc2 = b2s;
  for (int o = 0; o < 64; ++o) {
    const float4* wv4 = &w1s[o * 32];
    float4 a; a.x = 0.0f; a.y = 0.0f; a.z = 0.0f; a.w = 0.0f;
#pragma unroll
    for (int k = 0; k < 32; ++k) {
      float4 wv = wv4[k];
      a.x = fmaf(wv.x, hreg[k].x, a.x);
      a.y = fmaf(wv.y, hreg[k].y, a.y);
      a.z = fmaf(wv.z, hreg[k].z, a.z);
      a.w = fmaf(wv.w, hreg[k].w, a.w);
    }
    float z = b1s[o] + (a.x + a.y) + (a.z + a.w);
    z = fmaxf(z, 0.0f);
    acc2 = fmaf(w2s[o], z, acc2);
  }
  out[bt] = sigmoidf_(acc2);
}

extern "C" void kernel_launch(void* const* d_in, const int* in_sizes, int n_in,
                              void* d_out, int out_size, void* d_ws, size_t ws_size,
                              hipStream_t stream) {
  const float* x      = (const float*)d_in[0];
  const float* W_ih_f = (const float*)d_in[1];
  const float* W_hh_f = (const float*)d_in[2];
  const float* b_ih_f = (const float*)d_in[3];
  const float* b_hh_f = (const float*)d_in[4];
  const float* W_ih_b = (const float*)d_in[5];
  const float* W_hh_b = (const float*)d_in[6];
  const float* b_ih_b = (const float*)d_in[7];
  const float* b_hh_b = (const float*)d_in[8];
  const float* W1     = (const float*)d_in[9];
  const float* b1     = (const float*)d_in[10];
  const float* W2     = (const float*)d_in[11];
  const float* b2     = (const float*)d_in[12];
  float* out = (float*)d_out;
  __hip_bfloat16* hcat = (__hip_bfloat16*)d_ws;  // (B, T, 128) bf16 = 196.6 MB

  bilstm_kernel<<<dim3(2 * BB), dim3(256), 0, stream>>>(
      x, W_ih_f, W_hh_f, b_ih_f, b_hh_f, W_ih_b, W_hh_b, b_ih_b, b_hh_b, hcat);

  mlp_kernel<<<dim3(3000), dim3(256), 0, stream>>>((const unsigned*)hcat,
                                                   W1, b1, W2, b2, out);
}